// Round 13
// baseline (563.923 us; speedup 1.0000x reference)
//
#include <hip/hip_runtime.h>
#include <stdint.h>
#include <stddef.h>

#define B_ 4
#define S_ 2048
#define D_ 1024
#define H_ 16
#define DK_ 64
#define M_ (B_*S_)
#define NEGINF (-1e30f)
#define THR_ 8.0f

#if __has_builtin(__builtin_amdgcn_exp2f)
#define EXP2F(x) __builtin_amdgcn_exp2f(x)
#else
#define EXP2F(x) exp2f(x)
#endif

typedef _Float16 f16;
typedef __attribute__((ext_vector_type(8))) _Float16 f16x8;
typedef __attribute__((ext_vector_type(4))) _Float16 f16x4;
typedef __attribute__((ext_vector_type(4))) float f32x4;

// async global->LDS, 16B per lane; LDS dest = wave-uniform base + lane*16
__device__ __forceinline__ void gload16(const void* g, void* l) {
  __builtin_amdgcn_global_load_lds(
      (const __attribute__((address_space(1))) uint32_t*)g,
      (__attribute__((address_space(3))) uint32_t*)l, 16, 0, 0);
}

// K global layout (Kh): within each 64-token block, token r stored at row
// perm(r)=((r&3)<<4)|(r>>2); within each head's 64-dk row slice, 8-f16 chunk c
// stored at c^(perm(r)&7).  V global layout (Vt[bh][dk][key]): within each
// 64-key block, chunk c stored at c^(dk&7).  Consumers stage LINEARLY via
// global_load_lds and apply the XOR on ds_read.

// ---------------- fused prep: src cvt | weight cvt+transpose | masks ----------------
#define NB_SRC (M_*D_/8/256)        // 4096
#define NB_WT  1024
#define NB_MSK ((S_*S_/64 + B_*S_/64)/4)  // 16416
__global__ void k_prep(const float* __restrict__ src, f16* __restrict__ Xh,
                       const float* __restrict__ W0, const float* __restrict__ W1,
                       const float* __restrict__ W2, const float* __restrict__ W3,
                       f16* __restrict__ WtBase,
                       const int* __restrict__ am, const int* __restrict__ kp,
                       uint32_t* __restrict__ amw, uint32_t* __restrict__ kpw) {
  __shared__ float tile[64][65];
  const int bid = blockIdx.x, t = threadIdx.x;
  if (bid < NB_SRC) {
    int i = bid*256 + t;
    const f32x4* p = (const f32x4*)src;
    f32x4 a = p[2*i], b = p[2*i+1];
    f16x8 o;
    o[0]=(f16)a[0]; o[1]=(f16)a[1]; o[2]=(f16)a[2]; o[3]=(f16)a[3];
    o[4]=(f16)b[0]; o[5]=(f16)b[1]; o[6]=(f16)b[2]; o[7]=(f16)b[3];
    ((f16x8*)Xh)[i] = o;
  } else if (bid < NB_SRC + NB_WT) {
    int r = bid - NB_SRC;
    int z = r >> 8, rem = r & 255;
    const float* W = (z==0)?W0:(z==1)?W1:(z==2)?W2:W3;
    f16* Wt = WtBase + (size_t)z*D_*D_;
    int k0 = (rem & 15)*64, n0 = (rem >> 4)*64;
    int c4 = t & 15, r0 = t >> 4;
    #pragma unroll
    for (int i = 0; i < 4; i++) {
      int rr = r0 + i*16;
      f32x4 v = *(const f32x4*)&W[(size_t)(k0 + rr)*D_ + n0 + c4*4];
      tile[rr][c4*4+0]=v[0]; tile[rr][c4*4+1]=v[1]; tile[rr][c4*4+2]=v[2]; tile[rr][c4*4+3]=v[3];
    }
    __syncthreads();
    #pragma unroll
    for (int i = 0; i < 4; i++) {
      int nr = r0 + i*16;
      int kc = c4*4;
      f16x4 o;
      o[0]=(f16)tile[kc+0][nr]; o[1]=(f16)tile[kc+1][nr];
      o[2]=(f16)tile[kc+2][nr]; o[3]=(f16)tile[kc+3][nr];
      *(f16x4*)&Wt[(size_t)(n0+nr)*D_ + k0 + kc] = o;
    }
  } else {
    int g = (bid - NB_SRC - NB_WT)*4 + (t>>6);
    int lane = t & 63;
    const int NAM = S_*S_/64;
    int v; uint32_t* dst;
    if (g < NAM) { v = am[(size_t)g*64 + lane]; dst = amw + (size_t)g*2; }
    else         { int g2 = g - NAM; v = kp[(size_t)g2*64 + lane]; dst = kpw + (size_t)g2*2; }
    unsigned long long bal = __ballot(v != 0);
    if (lane == 0) { dst[0] = (uint32_t)bal; dst[1] = (uint32_t)(bal>>32); }
  }
}

// ---------------- fused QKV GEMM (m97 structure), z selects projection ----------------
__global__ __launch_bounds__(256, 2) void k_gemm_qkv(
    const f16* __restrict__ A, const f16* __restrict__ WtBase,
    const float* __restrict__ bq, const float* __restrict__ bk, const float* __restrict__ bv,
    f16* __restrict__ Qh, f16* __restrict__ Kh, f16* __restrict__ VtO) {
  __shared__ f16 As[128][64];
  __shared__ f16 Bs[128][64];
  const int z = blockIdx.z;
  const f16* Wt = WtBase + (size_t)z*D_*D_;
  const float* bias = (z==0) ? bq : (z==1) ? bk : bv;
  const int t = threadIdx.x;
  const int wave = t>>6, lane = t&63;
  const int lr = lane&15, lg = lane>>4;
  const int wr = wave>>1, wc = wave&1;
  const int m0 = blockIdx.y*128, n0 = blockIdx.x*128;
  const int srow = lane>>3, scol = (lane&7)*8;

  const f16* ga = A  + (size_t)m0*D_;
  const f16* gb = Wt + (size_t)n0*D_;

  f32x4 acc[4][4] = {};
  for (int kk=0; kk<16; kk++) {
    __syncthreads();
    #pragma unroll
    for (int i=0;i<4;i++){
      int rbase = i*32 + wave*8;
      gload16(&ga[(size_t)(rbase+srow)*D_ + kk*64 + scol], &As[rbase][0]);
      gload16(&gb[(size_t)(rbase+srow)*D_ + kk*64 + scol], &Bs[rbase][0]);
    }
    __syncthreads();
    #pragma unroll
    for (int s=0;s<2;s++) {
      f16x8 af[4], bf[4];
      #pragma unroll
      for (int i=0;i<4;i++) af[i] = *(const f16x8*)&As[wr*64 + i*16 + lr][s*32 + lg*8];
      #pragma unroll
      for (int i=0;i<4;i++) bf[i] = *(const f16x8*)&Bs[wc*64 + i*16 + lr][s*32 + lg*8];
      #pragma unroll
      for (int i=0;i<4;i++)
        #pragma unroll
        for (int j=0;j<4;j++)
          acc[i][j] = __builtin_amdgcn_mfma_f32_16x16x32_f16(af[i], bf[j], acc[i][j],0,0,0);
    }
  }
  #pragma unroll
  for (int fn=0; fn<4; fn++) {
    int n = n0 + wc*64 + fn*16 + lr;
    float bvv = bias[n];
    #pragma unroll
    for (int fm=0; fm<4; fm++) {
      int mrow = m0 + wr*64 + fm*16 + lg*4;
      if (z == 0) {
        #pragma unroll
        for (int j=0;j<4;j++) Qh[(size_t)(mrow+j)*D_ + n] = (f16)((acc[fm][fn][j] + bvv)*0.1803368801111204f);
      } else if (z == 1) {
        #pragma unroll
        for (int j=0;j<4;j++) {
          int m = mrow + j;
          int rr = m & 63;
          int pr = ((rr&3)<<4) | (rr>>2);
          int mg_ = (m & ~63) | pr;
          int cp = ((n>>3)&7) ^ (pr&7);
          int n2 = (n & ~63) | (cp<<3) | (n&7);
          Kh[(size_t)mg_*D_ + n2] = (f16)(acc[fm][fn][j] + bvv);
        }
      } else {
        int hh = n >> 6, dk = n & 63;
        int bb = mrow >> 11, ss = mrow & (S_-1);
        int cp = ((ss>>3)&7) ^ (dk&7);
        int ss2 = (ss & ~56) | (cp<<3);
        f16x4 o;
        #pragma unroll
        for (int j=0;j<4;j++) o[j] = (f16)(acc[fm][fn][j] + bvv);
        *(f16x4*)&VtO[((size_t)(bb*H_ + hh)*DK_ + dk)*S_ + ss2] = o;
      }
    }
  }
}

// ---------------- output GEMM: f32 out ----------------
__global__ __launch_bounds__(256, 2) void k_gemm_o(
    const f16* __restrict__ A, const f16* __restrict__ Wt,
    const float* __restrict__ bias, float* __restrict__ O) {
  __shared__ f16 As[128][64];
  __shared__ f16 Bs[128][64];
  const int t = threadIdx.x;
  const int wave = t>>6, lane = t&63;
  const int lr = lane&15, lg = lane>>4;
  const int wr = wave>>1, wc = wave&1;
  const int m0 = blockIdx.y*128, n0 = blockIdx.x*128;
  const int srow = lane>>3, scol = (lane&7)*8;

  const f16* ga = A  + (size_t)m0*D_;
  const f16* gb = Wt + (size_t)n0*D_;

  f32x4 acc[4][4] = {};
  for (int kk=0; kk<16; kk++) {
    __syncthreads();
    #pragma unroll
    for (int i=0;i<4;i++){
      int rbase = i*32 + wave*8;
      gload16(&ga[(size_t)(rbase+srow)*D_ + kk*64 + scol], &As[rbase][0]);
      gload16(&gb[(size_t)(rbase+srow)*D_ + kk*64 + scol], &Bs[rbase][0]);
    }
    __syncthreads();
    #pragma unroll
    for (int s=0;s<2;s++) {
      f16x8 af[4], bf[4];
      #pragma unroll
      for (int i=0;i<4;i++) af[i] = *(const f16x8*)&As[wr*64 + i*16 + lr][s*32 + lg*8];
      #pragma unroll
      for (int i=0;i<4;i++) bf[i] = *(const f16x8*)&Bs[wc*64 + i*16 + lr][s*32 + lg*8];
      #pragma unroll
      for (int i=0;i<4;i++)
        #pragma unroll
        for (int j=0;j<4;j++)
          acc[i][j] = __builtin_amdgcn_mfma_f32_16x16x32_f16(af[i], bf[j], acc[i][j],0,0,0);
    }
  }
  #pragma unroll
  for (int fn=0; fn<4; fn++) {
    int n = n0 + wc*64 + fn*16 + lr;
    float bv = bias[n];
    #pragma unroll
    for (int fm=0; fm<4; fm++) {
      int mrow = m0 + wr*64 + fm*16 + lg*4;
      #pragma unroll
      for (int j=0;j<4;j++) O[(size_t)(mrow+j)*D_ + n] = acc[fm][fn][j] + bv;
    }
  }
}

// ---------------- stats: QK^T + per-lane online defer-max/sum, K gload-dbuf ----------------
__global__ __launch_bounds__(256, 2) void k_stats(
    const f16* __restrict__ Qh, const f16* __restrict__ Kh,
    const uint32_t* __restrict__ amw, const uint32_t* __restrict__ kpw,
    float2* __restrict__ stats) {
  __shared__ f16 Kt[2][64][64];
  const int t = threadIdx.x, wave = t>>6, lane = t&63;
  const int lr = lane&15, lg = lane>>4;
  const int sh4 = 4*lr;
  const int fid = blockIdx.x;
  const int vid = (fid & 7)*64 + (fid >> 3);   // XCD swizzle
  const int bh = vid >> 3, qt = vid & 7;
  const int b = bh >> 4, h = bh & 15;
  const int qb = qt*256 + wave*64;

  const f16* kbase = Kh + (size_t)b*S_*D_ + h*64;
  const int srow = t>>3, sch = (t&7)*8, w8 = wave*8;
  const int ch0 = ((0|lg) ^ (lr&7))*8;
  const int ch1 = ((4|lg) ^ (lr&7))*8;

  f16x8 qf[4][2];
  #pragma unroll
  for (int qi=0; qi<4; qi++)
    #pragma unroll
    for (int s=0; s<2; s++)
      qf[qi][s] = *(const f16x8*)&Qh[(size_t)(b*S_ + qb + qi*16 + lr)*D_ + h*64 + s*32 + lg*8];

  float mu[4][4], l_[4][4];
  #pragma unroll
  for (int qi=0;qi<4;qi++)
    #pragma unroll
    for (int j=0;j<4;j++){ mu[qi][j]=NEGINF; l_[qi][j]=0.f; }

  gload16(&kbase[(size_t)srow*D_ + sch],      &Kt[0][w8][0]);
  gload16(&kbase[(size_t)(32+srow)*D_ + sch], &Kt[0][32+w8][0]);
  int cur = 0;
  for (int kt=0; kt<32; kt++) {
    __syncthreads();
    if (kt < 31) {
      int nxt = cur^1, k64 = (kt+1)*64;
      gload16(&kbase[(size_t)(k64+srow)*D_ + sch],    &Kt[nxt][w8][0]);
      gload16(&kbase[(size_t)(k64+32+srow)*D_ + sch], &Kt[nxt][32+w8][0]);
    }
    f32x4 sf[4][4] = {};
    #pragma unroll
    for (int s=0;s<2;s++) {
      const int chs = s ? ch1 : ch0;
      #pragma unroll
      for (int f=0;f<4;f++) {
        f16x8 kf = *(const f16x8*)&Kt[cur][f*16 + lr][chs];
        #pragma unroll
        for (int qi=0;qi<4;qi++)
          sf[qi][f] = __builtin_amdgcn_mfma_f32_16x16x32_f16(qf[qi][s], kf, sf[qi][f],0,0,0);
      }
    }
    uint32_t kw0 = kpw[b*64 + kt*2], kw1 = kpw[b*64 + kt*2 + 1];
    #pragma unroll
    for (int qi=0;qi<4;qi++)
      #pragma unroll
      for (int j=0;j<4;j++) {
        int qrow = qb + qi*16 + lg*4 + j;
        uint32_t a0 = amw[(size_t)qrow*64 + kt*2]     | kw0;
        uint32_t a1 = amw[(size_t)qrow*64 + kt*2 + 1] | kw1;
        int nb = (int)((((uint64_t)a1<<32) | a0) >> sh4) & 15;
        float x0 = (nb&1) ? NEGINF : sf[qi][0][j];
        float x1 = (nb&2) ? NEGINF : sf[qi][1][j];
        float x2 = (nb&4) ? NEGINF : sf[qi][2][j];
        float x3 = (nb&8) ? NEGINF : sf[qi][3][j];
        float tm = fmaxf(fmaxf(x0,x1), fmaxf(x2,x3));
        if (tm > mu[qi][j] + THR_) {   // per-lane defer-max (R7-verified math)
          float mo = (mu[qi][j] <= NEGINF) ? 0.f : mu[qi][j];
          l_[qi][j] *= EXP2F(mo - tm);
          mu[qi][j] = tm;
        }
        float mgv = (mu[qi][j] <= NEGINF) ? 0.f : mu[qi][j];
        l_[qi][j] += (EXP2F(x0-mgv)+EXP2F(x1-mgv))+(EXP2F(x2-mgv)+EXP2F(x3-mgv));
      }
    cur ^= 1;
  }
  // merge across the 16 lr-lanes of each row; publish (max, 1/l)
  #pragma unroll
  for (int qi=0;qi<4;qi++)
    #pragma unroll
    for (int j=0;j<4;j++) {
      float M = mu[qi][j];
      #pragma unroll
      for (int d=1; d<16; d<<=1) M = fmaxf(M, __shfl_xor(M, d));
      float M2 = (M <= NEGINF) ? 0.f : M;
      float mo = (mu[qi][j] <= NEGINF) ? 0.f : mu[qi][j];
      float lc = l_[qi][j] * EXP2F(mo - M2);
      #pragma unroll
      for (int d=1; d<16; d<<=1) lc += __shfl_xor(lc, d);
      if (lr == 0)
        stats[(size_t)bh*S_ + qb + qi*16 + lg*4 + j] =
            make_float2(M2, (lc > 0.f) ? 1.f/lc : 0.f);
    }
}

// ---------------- fused flash ∥ attn-writer (bid-split, union LDS 50KB -> 3 blocks/CU) ----------------
// bids 0..511: flash (qi=4, stats-read normalized P, per-qi-pair Pl slab, writes ctx).
// bids 512+: attn writer (128x128 tile, NT stores). Flash dispatched first ->
// ~2 flash + 1 attnw slot per CU: store stream overlaps flash compute.
__global__ __launch_bounds__(256, 2) void k_fa(
    const f16* __restrict__ Qh, const f16* __restrict__ Kh, const f16* __restrict__ Vt,
    const uint32_t* __restrict__ amw, const uint32_t* __restrict__ kpw,
    const float2* __restrict__ stats, float* __restrict__ attnp, f16* __restrict__ ctx) {
  __shared__ f16 lds[25600];   // 51.2KB: flash {Kt 2x4096 | Vtt 2x4096 | Pl 4x32x72}; attnw {Ks 128x64}
  const int bid = blockIdx.x;
  const int t = threadIdx.x, wave = t>>6, lane = t&63;
  const int lr = lane&15, lg = lane>>4;
  const int sh4 = 4*lr;
  const int ch0 = ((0|lg) ^ (lr&7))*8;
  const int ch1 = ((4|lg) ^ (lr&7))*8;
  const int srow = t>>3, sch = (t&7)*8, w8 = wave*8;

  if (bid < 512) {
    // ---------------- flash path ----------------
    const int fid = bid;
    const int vid = (fid & 7)*64 + (fid >> 3);
    const int bh = vid >> 3, qt = vid & 7;
    const int b = bh >> 4, h = bh & 15;
    const int qb = qt*256 + wave*64;
    const f16* kbase = Kh + (size_t)b*S_*D_ + h*64;
    const f16* vbase = Vt + (size_t)bh*DK_*S_;
    f16* const KTb = lds;                       // [2][64][64]
    f16* const VTb = lds + 8192;                // [2][64][64]
    f16* const PLb = lds + 16384 + wave*32*72;  // per-wave [32][72]

    f16x8 qf[4][2];
    #pragma unroll
    for (int qi=0; qi<4; qi++)
      #pragma unroll
      for (int s=0; s<2; s++)
        qf[qi][s] = *(const f16x8*)&Qh[(size_t)(b*S_ + qb + qi*16 + lr)*D_ + h*64 + s*32 + lg*8];

    float mgv[4][4], ilv[4][4];
    #pragma unroll
    for (int qi=0;qi<4;qi++)
      #pragma unroll
      for (int j=0;j<4;j++) {
        float2 sv = stats[(size_t)bh*S_ + qb + qi*16 + lg*4 + j];
        mgv[qi][j] = sv.x; ilv[qi][j] = sv.y;
      }

    f32x4 ct[4][4] = {};

    gload16(&kbase[(size_t)srow*D_ + sch],      KTb + w8*64);
    gload16(&kbase[(size_t)(32+srow)*D_ + sch], KTb + (32+w8)*64);
    gload16(&vbase[(size_t)srow*S_ + sch],      VTb + w8*64);
    gload16(&vbase[(size_t)(32+srow)*S_ + sch], VTb + (32+w8)*64);

    int cur = 0;
    for (int kt=0; kt<32; kt++) {
      __syncthreads();
      if (kt < 31) {
        int nxt = cur^1, k64 = (kt+1)*64;
        gload16(&kbase[(size_t)(k64+srow)*D_ + sch],      KTb + nxt*4096 + w8*64);
        gload16(&kbase[(size_t)(k64+32+srow)*D_ + sch],   KTb + nxt*4096 + (32+w8)*64);
        gload16(&vbase[(size_t)srow*S_ + k64 + sch],      VTb + nxt*4096 + w8*64);
        gload16(&vbase[(size_t)(32+srow)*S_ + k64 + sch], VTb + nxt*4096 + (32+w8)*64);
      }
      f32x4 sf[4][4] = {};
      #pragma unroll
      for (int s=0;s<2;s++) {
        const int chs = s ? ch1 : ch0;
        #pragma unroll
        for (int f=0;f<4;f++) {
          f16x8 kf = *(const f16x8*)&KTb[cur*4096 + (f*16 + lr)*64 + chs];
          #pragma unroll
          for (int qi=0;qi<4;qi++)
            sf[qi][f] = __builtin_amdgcn_mfma_f32_16x16x32_f16(qf[qi][s], kf, sf[qi][f],0,0,0);
        }
      }
      uint32_t kw0 = kpw[b*64 + kt*2], kw1 = kpw[b*64 + kt*2 + 1];
      #pragma unroll
      for (int p=0;p<2;p++) {
        #pragma unroll
        for (int half=0; half<2; half++) {
          const int qi = p*2 + half;
          #pragma unroll
          for (int j=0;j<4;j++) {
            int qrow = qb + qi*16 + lg*4 + j;
            uint32_t a0 = amw[(size_t)qrow*64 + kt*2]     | kw0;
            uint32_t a1 = amw[(size_t)qrow*64 + kt*2 + 1] | kw1;
            int nb = (int)((((uint64_t)a1<<32) | a0) >> sh4) & 15;
            float x0 = (nb&1) ? NEGINF : sf[qi][0][j];
            float x1 = (nb&2) ? NEGINF : sf[qi][1][j];
            float x2 = (nb&4) ? NEGINF : sf[qi][2][j];
            float x3 = (nb&8) ? NEGINF : sf[qi][3][j];
            float e0 = EXP2F(x0 - mgv[qi][j]) * ilv[qi][j];
            float e1 = EXP2F(x1 - mgv[qi][j]) * ilv[qi][j];
            float e2 = EXP2F(x2 - mgv[qi][j]) * ilv[qi][j];
            float e3 = EXP2F(x3 - mgv[qi][j]) * ilv[qi][j];
            f16x4 pv4; pv4[0]=(f16)e0; pv4[1]=(f16)e1; pv4[2]=(f16)e2; pv4[3]=(f16)e3;
            *(f16x4*)&PLb[(half*16 + lg*4 + j)*72 + sh4] = pv4;
          }
        }
        #pragma unroll
        for (int s=0;s<2;s++) {
          const int chs = s ? ch1 : ch0;
          f16x8 pb0 = *(const f16x8*)&PLb[lr*72 + s*32 + lg*8];
          f16x8 pb1 = *(const f16x8*)&PLb[(16 + lr)*72 + s*32 + lg*8];
          #pragma unroll
          for (int mf=0; mf<4; mf++) {
            f16x8 va = *(const f16x8*)&VTb[cur*4096 + (mf*16 + lr)*64 + chs];
            ct[mf][p*2]   = __builtin_amdgcn_mfma_f32_16x16x32_f16(va, pb0, ct[mf][p*2],0,0,0);
            ct[mf][p*2+1] = __builtin_amdgcn_mfma_f32_16x16x32_f16(va, pb1, ct[mf][p*2+1],0,0,0);
          }
        }
      }
      cur ^= 1;
    }
    // epilogue: ct already normalized (P was). Per pair: bounce 32 rows -> ctx
    #pragma unroll
    for (int p=0;p<2;p++) {
      #pragma unroll
      for (int mf=0; mf<4; mf++)
        #pragma unroll
        for (int half=0; half<2; half++) {
          const int qi = p*2 + half;
          f16x4 o;
          #pragma unroll
          for (int j=0;j<4;j++) o[j] = (f16)ct[mf][qi][j];
          *(f16x4*)&PLb[(half*16 + lr)*72 + mf*16 + lg*4] = o;
        }
      __builtin_amdgcn_s_waitcnt(0);
      #pragma unroll
      for (int i=0;i<4;i++) {
        int idx = i*64 + lane;
        int row = idx >> 3, ch = idx & 7;
        f16x8 o = *(const f16x8*)&PLb[row*72 + ch*8];
        *(f16x8*)&ctx[(size_t)(b*S_ + qb + p*32 + row)*D_ + h*64 + ch*8] = o;
      }
    }
  } else {
    // ---------------- attn-writer path ----------------
    const int aid = bid - 512;
    const int ktb = aid & 15, qt = (aid>>4)&15, bh = aid>>8;
    const int b = bh >> 4, h = bh & 15;
    const int qb = qt*128, kb = ktb*128;
    f16* const Ks = lds;   // [128][64]

    #pragma unroll
    for (int q2=0; q2<4; q2++)
      gload16(&Kh[(size_t)(b*S_ + kb + q2*32 + srow)*D_ + h*64 + sch], Ks + (q2*32 + w8)*64);

    f16x8 qf[2][2];
    #pragma unroll
    for (int qi=0; qi<2; qi++)
      #pragma unroll
      for (int s=0; s<2; s++)
        qf[qi][s] = *(const f16x8*)&Qh[(size_t)(b*S_ + qb + wave*32 + qi*16 + lr)*D_ + h*64 + s*32 + lg*8];
    __syncthreads();   // drains gload_lds

    f32x4 sf[2][8] = {};
    #pragma unroll
    for (int s=0;s<2;s++) {
      const int chs = s ? ch1 : ch0;
      #pragma unroll
      for (int f=0;f<8;f++) {
        f16x8 kf = *(const f16x8*)&Ks[(f*16 + lr)*64 + chs];
        #pragma unroll
        for (int qi=0;qi<2;qi++)
          sf[qi][f] = __builtin_amdgcn_mfma_f32_16x16x32_f16(qf[qi][s], kf, sf[qi][f],0,0,0);
      }
    }

    uint32_t kw[4];
    #pragma unroll
    for (int i=0;i<4;i++) kw[i] = kpw[b*64 + ktb*4 + i];

    #pragma unroll
    for (int qi=0;qi<2;qi++)
      #pragma unroll
      for (int j=0;j<4;j++) {
        int qrow = qb + wave*32 + qi*16 + lg*4 + j;
        float2 st = stats[(size_t)bh*S_ + qrow];
        #pragma unroll
        for (int half=0; half<2; half++) {
          uint32_t a0 = amw[(size_t)qrow*64 + ktb*4 + half*2]     | kw[half*2];
          uint32_t a1 = amw[(size_t)qrow*64 + ktb*4 + half*2 + 1] | kw[half*2+1];
          int nb = (int)((((uint64_t)a1<<32) | a0) >> sh4) & 15;
          float x0 = (nb&1) ? NEGINF : sf[qi][half*4+0][j];
          float x1 = (nb&2) ? NEGINF : sf[qi][half*4+1][j];
          float x2 = (nb&4) ? NEGINF : sf[qi][half*4+2][j];
          float x3 = (nb&8) ? NEGINF : sf[qi][half*4+3][j];
          f32x4 ev;
          ev[0] = EXP2F(x0 - st.x) * st.y;
          ev[1] = EXP2F(x1 - st.x) * st.y;
          ev[2] = EXP2F(x2 - st.x) * st.y;
          ev[3] = EXP2F(x3 - st.x) * st.y;
          __builtin_nontemporal_store(ev,
              (f32x4*)&attnp[((size_t)bh*S_ + qrow)*S_ + kb + half*64 + sh4]);
        }
      }
  }
}

// ---------------- launch ----------------
extern "C" void kernel_launch(void* const* d_in, const int* in_sizes, int n_in,
                              void* d_out, int out_size, void* d_ws, size_t ws_size,
                              hipStream_t stream) {
  const float* src = (const float*)d_in[0];
  const int*   am  = (const int*)d_in[1];
  const int*   kp  = (const int*)d_in[2];
  const float* Wq  = (const float*)d_in[3];
  const float* bq  = (const float*)d_in[4];
  const float* Wk  = (const float*)d_in[5];
  const float* bk  = (const float*)d_in[6];
  const float* Wv  = (const float*)d_in[7];
  const float* bv  = (const float*)d_in[8];
  const float* Wo  = (const float*)d_in[9];
  const float* bo  = (const float*)d_in[10];

  const size_t need = (size_t)M_*D_*2        // Xh
                    + (size_t)4*D_*D_*2      // Wth
                    + (size_t)4*M_*D_*2      // Qh,Kh,Vt,CT
                    + (size_t)S_*S_/8        // amw
                    + (size_t)B_*S_/8        // kpw
                    + (size_t)M_*8;          // stats
  if (ws_size < need) return;

  char* w = (char*)d_ws;
  f16* Xh  = (f16*)w;  w += (size_t)M_*D_*2;
  f16* Wth = (f16*)w;  w += (size_t)4*D_*D_*2;
  f16* Qh  = (f16*)w;  w += (size_t)M_*D_*2;
  f16* Kh  = (f16*)w;  w += (size_t)M_*D_*2;
  f16* Vt  = (f16*)w;  w += (size_t)M_*D_*2;
  f16* CT  = (f16*)w;  w += (size_t)M_*D_*2;
  uint32_t* amw = (uint32_t*)w; w += (size_t)S_*S_/8;
  uint32_t* kpw = (uint32_t*)w; w += (size_t)B_*S_/8;
  float2* stats = (float2*)w;

  float* outp  = (float*)d_out;
  float* attnp = outp + (size_t)M_*D_;

  k_prep<<<NB_SRC + NB_WT + NB_MSK, 256, 0, stream>>>(
      src, Xh, Wq, Wk, Wv, Wo, Wth, am, kp, amw, kpw);
  k_gemm_qkv<<<dim3(8,64,3), 256, 0, stream>>>(Xh, Wth, bq, bk, bv, Qh, Kh, Vt);
  k_stats<<<512, 256, 0, stream>>>(Qh, Kh, amw, kpw, stats);
  k_fa<<<512 + 16384, 256, 0, stream>>>(Qh, Kh, Vt, amw, kpw, stats, attnp, CT);
  k_gemm_o<<<dim3(8,64), 256, 0, stream>>>(CT, Wth + 3*(size_t)D_*D_, bo, outp);
}

// Round 14
// 474.533 us; speedup vs baseline: 1.1884x; 1.1884x over previous
//
#include <hip/hip_runtime.h>
#include <stdint.h>
#include <stddef.h>

#define B_ 4
#define S_ 2048
#define D_ 1024
#define H_ 16
#define DK_ 64
#define M_ (B_*S_)
#define NEGINF (-1e30f)
#define THR_ 8.0f

#if __has_builtin(__builtin_amdgcn_exp2f)
#define EXP2F(x) __builtin_amdgcn_exp2f(x)
#else
#define EXP2F(x) exp2f(x)
#endif

typedef _Float16 f16;
typedef __attribute__((ext_vector_type(8))) _Float16 f16x8;
typedef __attribute__((ext_vector_type(4))) _Float16 f16x4;
typedef __attribute__((ext_vector_type(4))) float f32x4;

// async global->LDS, 16B per lane; LDS dest = wave-uniform base + lane*16
__device__ __forceinline__ void gload16(const void* g, void* l) {
  __builtin_amdgcn_global_load_lds(
      (const __attribute__((address_space(1))) uint32_t*)g,
      (__attribute__((address_space(3))) uint32_t*)l, 16, 0, 0);
}

// K global layout (Kh): within each 64-token block, token r stored at row
// perm(r)=((r&3)<<4)|(r>>2); within each head's 64-dk row slice, 8-f16 chunk c
// stored at c^(perm(r)&7).  V global layout (Vt[bh][dk][key]): within each
// 64-key block, chunk c stored at c^(dk&7).  Consumers stage LINEARLY via
// global_load_lds and apply the XOR on ds_read.

// ---------------- fused prep: src cvt | weight cvt+transpose | masks ----------------
#define NB_SRC (M_*D_/8/256)        // 4096
#define NB_WT  1024
#define NB_MSK ((S_*S_/64 + B_*S_/64)/4)  // 16416
__global__ void k_prep(const float* __restrict__ src, f16* __restrict__ Xh,
                       const float* __restrict__ W0, const float* __restrict__ W1,
                       const float* __restrict__ W2, const float* __restrict__ W3,
                       f16* __restrict__ WtBase,
                       const int* __restrict__ am, const int* __restrict__ kp,
                       uint32_t* __restrict__ amw, uint32_t* __restrict__ kpw) {
  __shared__ float tile[64][65];
  const int bid = blockIdx.x, t = threadIdx.x;
  if (bid < NB_SRC) {
    int i = bid*256 + t;
    const f32x4* p = (const f32x4*)src;
    f32x4 a = p[2*i], b = p[2*i+1];
    f16x8 o;
    o[0]=(f16)a[0]; o[1]=(f16)a[1]; o[2]=(f16)a[2]; o[3]=(f16)a[3];
    o[4]=(f16)b[0]; o[5]=(f16)b[1]; o[6]=(f16)b[2]; o[7]=(f16)b[3];
    ((f16x8*)Xh)[i] = o;
  } else if (bid < NB_SRC + NB_WT) {
    int r = bid - NB_SRC;
    int z = r >> 8, rem = r & 255;
    const float* W = (z==0)?W0:(z==1)?W1:(z==2)?W2:W3;
    f16* Wt = WtBase + (size_t)z*D_*D_;
    int k0 = (rem & 15)*64, n0 = (rem >> 4)*64;
    int c4 = t & 15, r0 = t >> 4;
    #pragma unroll
    for (int i = 0; i < 4; i++) {
      int rr = r0 + i*16;
      f32x4 v = *(const f32x4*)&W[(size_t)(k0 + rr)*D_ + n0 + c4*4];
      tile[rr][c4*4+0]=v[0]; tile[rr][c4*4+1]=v[1]; tile[rr][c4*4+2]=v[2]; tile[rr][c4*4+3]=v[3];
    }
    __syncthreads();
    #pragma unroll
    for (int i = 0; i < 4; i++) {
      int nr = r0 + i*16;
      int kc = c4*4;
      f16x4 o;
      o[0]=(f16)tile[kc+0][nr]; o[1]=(f16)tile[kc+1][nr];
      o[2]=(f16)tile[kc+2][nr]; o[3]=(f16)tile[kc+3][nr];
      *(f16x4*)&Wt[(size_t)(n0+nr)*D_ + k0 + kc] = o;
    }
  } else {
    int g = (bid - NB_SRC - NB_WT)*4 + (t>>6);
    int lane = t & 63;
    const int NAM = S_*S_/64;
    int v; uint32_t* dst;
    if (g < NAM) { v = am[(size_t)g*64 + lane]; dst = amw + (size_t)g*2; }
    else         { int g2 = g - NAM; v = kp[(size_t)g2*64 + lane]; dst = kpw + (size_t)g2*2; }
    unsigned long long bal = __ballot(v != 0);
    if (lane == 0) { dst[0] = (uint32_t)bal; dst[1] = (uint32_t)(bal>>32); }
  }
}

// ---------------- fused QKV GEMM (m97 structure), z selects projection ----------------
__global__ __launch_bounds__(256, 2) void k_gemm_qkv(
    const f16* __restrict__ A, const f16* __restrict__ WtBase,
    const float* __restrict__ bq, const float* __restrict__ bk, const float* __restrict__ bv,
    f16* __restrict__ Qh, f16* __restrict__ Kh, f16* __restrict__ VtO) {
  __shared__ f16 As[128][64];
  __shared__ f16 Bs[128][64];
  const int z = blockIdx.z;
  const f16* Wt = WtBase + (size_t)z*D_*D_;
  const float* bias = (z==0) ? bq : (z==1) ? bk : bv;
  const int t = threadIdx.x;
  const int wave = t>>6, lane = t&63;
  const int lr = lane&15, lg = lane>>4;
  const int wr = wave>>1, wc = wave&1;
  const int m0 = blockIdx.y*128, n0 = blockIdx.x*128;
  const int srow = lane>>3, scol = (lane&7)*8;

  const f16* ga = A  + (size_t)m0*D_;
  const f16* gb = Wt + (size_t)n0*D_;

  f32x4 acc[4][4] = {};
  for (int kk=0; kk<16; kk++) {
    __syncthreads();
    #pragma unroll
    for (int i=0;i<4;i++){
      int rbase = i*32 + wave*8;
      gload16(&ga[(size_t)(rbase+srow)*D_ + kk*64 + scol], &As[rbase][0]);
      gload16(&gb[(size_t)(rbase+srow)*D_ + kk*64 + scol], &Bs[rbase][0]);
    }
    __syncthreads();
    #pragma unroll
    for (int s=0;s<2;s++) {
      f16x8 af[4], bf[4];
      #pragma unroll
      for (int i=0;i<4;i++) af[i] = *(const f16x8*)&As[wr*64 + i*16 + lr][s*32 + lg*8];
      #pragma unroll
      for (int i=0;i<4;i++) bf[i] = *(const f16x8*)&Bs[wc*64 + i*16 + lr][s*32 + lg*8];
      #pragma unroll
      for (int i=0;i<4;i++)
        #pragma unroll
        for (int j=0;j<4;j++)
          acc[i][j] = __builtin_amdgcn_mfma_f32_16x16x32_f16(af[i], bf[j], acc[i][j],0,0,0);
    }
  }
  #pragma unroll
  for (int fn=0; fn<4; fn++) {
    int n = n0 + wc*64 + fn*16 + lr;
    float bvv = bias[n];
    #pragma unroll
    for (int fm=0; fm<4; fm++) {
      int mrow = m0 + wr*64 + fm*16 + lg*4;
      if (z == 0) {
        #pragma unroll
        for (int j=0;j<4;j++) Qh[(size_t)(mrow+j)*D_ + n] = (f16)((acc[fm][fn][j] + bvv)*0.1803368801111204f);
      } else if (z == 1) {
        #pragma unroll
        for (int j=0;j<4;j++) {
          int m = mrow + j;
          int rr = m & 63;
          int pr = ((rr&3)<<4) | (rr>>2);
          int mg_ = (m & ~63) | pr;
          int cp = ((n>>3)&7) ^ (pr&7);
          int n2 = (n & ~63) | (cp<<3) | (n&7);
          Kh[(size_t)mg_*D_ + n2] = (f16)(acc[fm][fn][j] + bvv);
        }
      } else {
        int hh = n >> 6, dk = n & 63;
        int bb = mrow >> 11, ss = mrow & (S_-1);
        int cp = ((ss>>3)&7) ^ (dk&7);
        int ss2 = (ss & ~56) | (cp<<3);
        f16x4 o;
        #pragma unroll
        for (int j=0;j<4;j++) o[j] = (f16)(acc[fm][fn][j] + bvv);
        *(f16x4*)&VtO[((size_t)(bb*H_ + hh)*DK_ + dk)*S_ + ss2] = o;
      }
    }
  }
}

// ---------------- single-pass flash (R12 body): 64 q-rows/wave (qi=4) ----------------
__global__ __launch_bounds__(256, 2) void k_flash(
    const f16* __restrict__ Qh, const f16* __restrict__ Kh, const f16* __restrict__ Vt,
    const uint32_t* __restrict__ amw, const uint32_t* __restrict__ kpw,
    float2* __restrict__ stats, f16* __restrict__ ctx) {
  __shared__ f16 Kt[2][64][64];
  __shared__ f16 Vtt[2][64][64];
  __shared__ f16 Pl[4][64][72];
  __shared__ float ssc[4][4][16];

  const int t = threadIdx.x, wave = t>>6, lane = t&63;
  const int lr = lane&15, lg = lane>>4;
  const int sh4 = 4*lr;
  const int flat = blockIdx.x;
  const int vid = (flat & 7)*64 + (flat >> 3);   // XCD swizzle: 64 vids per XCD
  const int bh = vid >> 3, qt = vid & 7;
  const int b = bh >> 4, h = bh & 15;
  const int qb = qt*256 + wave*64;               // this wave's 64 q rows

  const f16* kbase = Kh + (size_t)b*S_*D_ + h*64;
  const f16* vbase = Vt + (size_t)bh*DK_*S_;
  const int srow = t>>3, sch = (t&7)*8;
  const int w8 = wave*8;
  const int ch0 = ((0|lg) ^ (lr&7))*8;
  const int ch1 = ((4|lg) ^ (lr&7))*8;

  f16x8 qf[4][2];
  #pragma unroll
  for (int qi=0; qi<4; qi++)
    #pragma unroll
    for (int s=0; s<2; s++)
      qf[qi][s] = *(const f16x8*)&Qh[(size_t)(b*S_ + qb + qi*16 + lr)*D_ + h*64 + s*32 + lg*8];

  float mu[4][4], l_[4][4];
  #pragma unroll
  for (int qi=0;qi<4;qi++)
    #pragma unroll
    for (int j=0;j<4;j++){ mu[qi][j]=NEGINF; l_[qi][j]=0.f; }
  f32x4 ct[4][4] = {};

  gload16(&kbase[(size_t)srow*D_ + sch],        &Kt[0][w8][0]);
  gload16(&kbase[(size_t)(32+srow)*D_ + sch],   &Kt[0][32+w8][0]);
  gload16(&vbase[(size_t)srow*S_ + sch],        &Vtt[0][w8][0]);
  gload16(&vbase[(size_t)(32+srow)*S_ + sch],   &Vtt[0][32+w8][0]);

  int cur = 0;
  for (int kt=0; kt<32; kt++) {
    __syncthreads();
    if (kt < 31) {
      int nxt = cur^1, k64 = (kt+1)*64;
      gload16(&kbase[(size_t)(k64+srow)*D_ + sch],      &Kt[nxt][w8][0]);
      gload16(&kbase[(size_t)(k64+32+srow)*D_ + sch],   &Kt[nxt][32+w8][0]);
      gload16(&vbase[(size_t)srow*S_ + k64 + sch],      &Vtt[nxt][w8][0]);
      gload16(&vbase[(size_t)(32+srow)*S_ + k64 + sch], &Vtt[nxt][32+w8][0]);
    }
    f32x4 sf[4][4] = {};
    #pragma unroll
    for (int s=0;s<2;s++) {
      const int chs = s ? ch1 : ch0;
      #pragma unroll
      for (int f=0;f<4;f++) {
        f16x8 kf = *(const f16x8*)&Kt[cur][f*16 + lr][chs];
        #pragma unroll
        for (int qi=0;qi<4;qi++)
          sf[qi][f] = __builtin_amdgcn_mfma_f32_16x16x32_f16(qf[qi][s], kf, sf[qi][f],0,0,0);
      }
    }
    uint32_t kw0 = kpw[b*64 + kt*2], kw1 = kpw[b*64 + kt*2 + 1];
    #pragma unroll
    for (int qi=0;qi<4;qi++) {
      float tmq[4];
      #pragma unroll
      for (int j=0;j<4;j++) {
        int qrow = qb + qi*16 + lg*4 + j;
        uint32_t a0 = amw[(size_t)qrow*64 + kt*2]     | kw0;
        uint32_t a1 = amw[(size_t)qrow*64 + kt*2 + 1] | kw1;
        int nb = (int)((((uint64_t)a1<<32) | a0) >> sh4) & 15;
        sf[qi][0][j] = (nb&1) ? NEGINF : sf[qi][0][j];
        sf[qi][1][j] = (nb&2) ? NEGINF : sf[qi][1][j];
        sf[qi][2][j] = (nb&4) ? NEGINF : sf[qi][2][j];
        sf[qi][3][j] = (nb&8) ? NEGINF : sf[qi][3][j];
        tmq[j] = fmaxf(fmaxf(sf[qi][0][j], sf[qi][1][j]),
                       fmaxf(sf[qi][2][j], sf[qi][3][j]));
      }
      int need = 0;
      #pragma unroll
      for (int j=0;j<4;j++) need |= (tmq[j] > mu[qi][j] + THR_) ? 1 : 0;
      if (__any(need)) {
        #pragma unroll
        for (int j=0;j<4;j++) {
          float gm = tmq[j];
          #pragma unroll
          for (int d=1; d<16; d<<=1) gm = fmaxf(gm, __shfl_xor(gm, d));
          float mnew = fmaxf(mu[qi][j], gm);
          float mgo = (mu[qi][j] <= NEGINF) ? 0.f : mu[qi][j];
          float mgn = (mnew <= NEGINF) ? 0.f : mnew;
          float sc = EXP2F(mgo - mgn);
          l_[qi][j] *= sc;
          mu[qi][j] = mnew;
          if (lr == 0) ssc[wave][qi][lg*4+j] = sc;
        }
        asm volatile("s_waitcnt lgkmcnt(0)" ::: "memory");
        __builtin_amdgcn_sched_barrier(0);
        float svv = ssc[wave][qi][lr];
        #pragma unroll
        for (int mf=0; mf<4; mf++)
          #pragma unroll
          for (int c=0;c<4;c++) ct[mf][qi][c] *= svv;
      }
      #pragma unroll
      for (int j=0;j<4;j++) {
        float mgv = (mu[qi][j] <= NEGINF) ? 0.f : mu[qi][j];
        float e0 = EXP2F(sf[qi][0][j] - mgv);
        float e1 = EXP2F(sf[qi][1][j] - mgv);
        float e2 = EXP2F(sf[qi][2][j] - mgv);
        float e3 = EXP2F(sf[qi][3][j] - mgv);
        l_[qi][j] += (e0+e1)+(e2+e3);
        f16x4 pv4; pv4[0]=(f16)e0; pv4[1]=(f16)e1; pv4[2]=(f16)e2; pv4[3]=(f16)e3;
        *(f16x4*)&Pl[wave][qi*16 + lg*4 + j][sh4] = pv4;
      }
    }
    #pragma unroll
    for (int s=0;s<2;s++) {
      const int chs = s ? ch1 : ch0;
      f16x8 pb[4];
      #pragma unroll
      for (int qi=0;qi<4;qi++)
        pb[qi] = *(const f16x8*)&Pl[wave][qi*16 + lr][s*32 + lg*8];
      #pragma unroll
      for (int mf=0; mf<4; mf++) {
        f16x8 va = *(const f16x8*)&Vtt[cur][mf*16 + lr][chs];
        #pragma unroll
        for (int qi=0;qi<4;qi++)
          ct[mf][qi] = __builtin_amdgcn_mfma_f32_16x16x32_f16(va, pb[qi], ct[mf][qi],0,0,0);
      }
    }
    cur ^= 1;
  }

  #pragma unroll
  for (int qi=0;qi<4;qi++)
    #pragma unroll
    for (int j=0;j<4;j++) {
      float ls = l_[qi][j];
      #pragma unroll
      for (int d=1; d<16; d<<=1) ls += __shfl_xor(ls, d);
      float ilv = (ls > 0.f) ? 1.f/ls : 0.f;
      if (lr == 0) {
        ssc[wave][qi][lg*4+j] = ilv;
        float mgv = (mu[qi][j] <= NEGINF) ? 0.f : mu[qi][j];
        stats[(size_t)bh*S_ + qb + qi*16 + lg*4 + j] = make_float2(mgv, ilv);
      }
    }
  asm volatile("s_waitcnt lgkmcnt(0)" ::: "memory");
  __builtin_amdgcn_sched_barrier(0);
  float il[4];
  #pragma unroll
  for (int qi=0;qi<4;qi++) il[qi] = ssc[wave][qi][lr];

  #pragma unroll
  for (int mf=0; mf<4; mf++)
    #pragma unroll
    for (int qi=0; qi<4; qi++) {
      f16x4 o;
      #pragma unroll
      for (int j=0;j<4;j++) o[j] = (f16)(ct[mf][qi][j] * il[qi]);
      *(f16x4*)&Pl[wave][qi*16 + lr][mf*16 + lg*4] = o;
    }
  __builtin_amdgcn_s_waitcnt(0);
  #pragma unroll
  for (int i=0;i<8;i++) {
    int idx = i*64 + lane;
    int row = idx >> 3, ch = idx & 7;
    f16x8 o = *(const f16x8*)&Pl[wave][row][ch*8];
    *(f16x8*)&ctx[(size_t)(b*S_ + qb + row)*D_ + h*64 + ch*8] = o;
  }
}

// ---------------- fused output-GEMM ∥ attn-writer: sparse interleave ----------------
// bid = 33q + r. r==0 -> gemm_o block q (512 total, short, MFMA-heavy); r>=1 ->
// attnw block 32q + r-1 (16384 total, store-heavy). 1 gemm per 32 attnw in
// dispatch order: gemm MFMA work hides under the NT-store stream.
__global__ __launch_bounds__(256, 2) void k_oa(
    const f16* __restrict__ A, const f16* __restrict__ Wt,
    const float* __restrict__ bias, float* __restrict__ O,
    const f16* __restrict__ Qh, const f16* __restrict__ Kh,
    const uint32_t* __restrict__ amw, const uint32_t* __restrict__ kpw,
    const float2* __restrict__ stats, float* __restrict__ attnp) {
  __shared__ f16 lds[16384];   // 32KB union: gemm {As|Bs 8192+8192}, attnw {Ks 8192}
  const int bid = blockIdx.x;
  const int q = bid / 33, r = bid - q*33;
  const int t = threadIdx.x;
  const int wave = t>>6, lane = t&63;
  const int lr = lane&15, lg = lane>>4;
  const int srow2 = t>>3, sch2 = (t&7)*8, w8 = wave*8;

  if (r == 0) {
    // ---------------- gemm_o block q ----------------
    f16 (*As)[64] = (f16(*)[64])lds;
    f16 (*Bs)[64] = (f16(*)[64])(lds + 8192);
    const int wr = wave>>1, wc = wave&1;
    const int m0 = (q>>3)*128, n0 = (q&7)*128;
    const int srow = lane>>3, scol = (lane&7)*8;
    const f16* ga = A  + (size_t)m0*D_;
    const f16* gb = Wt + (size_t)n0*D_;

    f32x4 acc[4][4] = {};
    for (int kk=0; kk<16; kk++) {
      __syncthreads();
      #pragma unroll
      for (int i=0;i<4;i++){
        int rbase = i*32 + wave*8;
        gload16(&ga[(size_t)(rbase+srow)*D_ + kk*64 + scol], &As[rbase][0]);
        gload16(&gb[(size_t)(rbase+srow)*D_ + kk*64 + scol], &Bs[rbase][0]);
      }
      __syncthreads();
      #pragma unroll
      for (int s=0;s<2;s++) {
        f16x8 af[4], bf[4];
        #pragma unroll
        for (int i=0;i<4;i++) af[i] = *(const f16x8*)&As[wr*64 + i*16 + lr][s*32 + lg*8];
        #pragma unroll
        for (int i=0;i<4;i++) bf[i] = *(const f16x8*)&Bs[wc*64 + i*16 + lr][s*32 + lg*8];
        #pragma unroll
        for (int i=0;i<4;i++)
          #pragma unroll
          for (int j=0;j<4;j++)
            acc[i][j] = __builtin_amdgcn_mfma_f32_16x16x32_f16(af[i], bf[j], acc[i][j],0,0,0);
      }
    }
    #pragma unroll
    for (int fn=0; fn<4; fn++) {
      int n = n0 + wc*64 + fn*16 + lr;
      float bv = bias[n];
      #pragma unroll
      for (int fm=0; fm<4; fm++) {
        int mrow = m0 + wr*64 + fm*16 + lg*4;
        #pragma unroll
        for (int j=0;j<4;j++) O[(size_t)(mrow+j)*D_ + n] = acc[fm][fn][j] + bv;
      }
    }
  } else {
    // ---------------- attn-writer block ----------------
    const int aid = q*32 + (r-1);
    const int ktb = aid & 15, qt = (aid>>4)&15, bh = aid>>8;
    const int b = bh >> 4, h = bh & 15;
    const int qb = qt*128, kb = ktb*128;
    const int sh4 = 4*lr;
    const int ch0 = ((0|lg) ^ (lr&7))*8;
    const int ch1 = ((4|lg) ^ (lr&7))*8;
    f16 (*Ks)[64] = (f16(*)[64])lds;

    #pragma unroll
    for (int q2=0; q2<4; q2++)
      gload16(&Kh[(size_t)(b*S_ + kb + q2*32 + srow2)*D_ + h*64 + sch2], &Ks[q2*32 + w8][0]);

    f16x8 qf[2][2];
    #pragma unroll
    for (int qi=0; qi<2; qi++)
      #pragma unroll
      for (int s=0; s<2; s++)
        qf[qi][s] = *(const f16x8*)&Qh[(size_t)(b*S_ + qb + wave*32 + qi*16 + lr)*D_ + h*64 + s*32 + lg*8];
    __syncthreads();   // drains gload_lds

    f32x4 sf[2][8] = {};
    #pragma unroll
    for (int s=0;s<2;s++) {
      const int chs = s ? ch1 : ch0;
      #pragma unroll
      for (int f=0;f<8;f++) {
        f16x8 kf = *(const f16x8*)&Ks[f*16 + lr][chs];
        #pragma unroll
        for (int qi=0;qi<2;qi++)
          sf[qi][f] = __builtin_amdgcn_mfma_f32_16x16x32_f16(qf[qi][s], kf, sf[qi][f],0,0,0);
      }
    }

    uint32_t kw[4];
    #pragma unroll
    for (int i=0;i<4;i++) kw[i] = kpw[b*64 + ktb*4 + i];

    #pragma unroll
    for (int qi=0;qi<2;qi++)
      #pragma unroll
      for (int j=0;j<4;j++) {
        int qrow = qb + wave*32 + qi*16 + lg*4 + j;
        float2 st = stats[(size_t)bh*S_ + qrow];
        #pragma unroll
        for (int half=0; half<2; half++) {
          uint32_t a0 = amw[(size_t)qrow*64 + ktb*4 + half*2]     | kw[half*2];
          uint32_t a1 = amw[(size_t)qrow*64 + ktb*4 + half*2 + 1] | kw[half*2+1];
          int nb = (int)((((uint64_t)a1<<32) | a0) >> sh4) & 15;
          float x0 = (nb&1) ? NEGINF : sf[qi][half*4+0][j];
          float x1 = (nb&2) ? NEGINF : sf[qi][half*4+1][j];
          float x2 = (nb&4) ? NEGINF : sf[qi][half*4+2][j];
          float x3 = (nb&8) ? NEGINF : sf[qi][half*4+3][j];
          f32x4 ev;
          ev[0] = EXP2F(x0 - st.x) * st.y;
          ev[1] = EXP2F(x1 - st.x) * st.y;
          ev[2] = EXP2F(x2 - st.x) * st.y;
          ev[3] = EXP2F(x3 - st.x) * st.y;
          __builtin_nontemporal_store(ev,
              (f32x4*)&attnp[((size_t)bh*S_ + qrow)*S_ + kb + half*64 + sh4]);
        }
      }
  }
}

// ---------------- launch ----------------
extern "C" void kernel_launch(void* const* d_in, const int* in_sizes, int n_in,
                              void* d_out, int out_size, void* d_ws, size_t ws_size,
                              hipStream_t stream) {
  const float* src = (const float*)d_in[0];
  const int*   am  = (const int*)d_in[1];
  const int*   kp  = (const int*)d_in[2];
  const float* Wq  = (const float*)d_in[3];
  const float* bq  = (const float*)d_in[4];
  const float* Wk  = (const float*)d_in[5];
  const float* bk  = (const float*)d_in[6];
  const float* Wv  = (const float*)d_in[7];
  const float* bv  = (const float*)d_in[8];
  const float* Wo  = (const float*)d_in[9];
  const float* bo  = (const float*)d_in[10];

  const size_t need = (size_t)M_*D_*2        // Xh
                    + (size_t)4*D_*D_*2      // Wth
                    + (size_t)4*M_*D_*2      // Qh,Kh,Vt,CT
                    + (size_t)S_*S_/8        // amw
                    + (size_t)B_*S_/8        // kpw
                    + (size_t)M_*8;          // stats
  if (ws_size < need) return;

  char* w = (char*)d_ws;
  f16* Xh  = (f16*)w;  w += (size_t)M_*D_*2;
  f16* Wth = (f16*)w;  w += (size_t)4*D_*D_*2;
  f16* Qh  = (f16*)w;  w += (size_t)M_*D_*2;
  f16* Kh  = (f16*)w;  w += (size_t)M_*D_*2;
  f16* Vt  = (f16*)w;  w += (size_t)M_*D_*2;
  f16* CT  = (f16*)w;  w += (size_t)M_*D_*2;
  uint32_t* amw = (uint32_t*)w; w += (size_t)S_*S_/8;
  uint32_t* kpw = (uint32_t*)w; w += (size_t)B_*S_/8;
  float2* stats = (float2*)w;

  float* outp  = (float*)d_out;
  float* attnp = outp + (size_t)M_*D_;

  k_prep<<<NB_SRC + NB_WT + NB_MSK, 256, 0, stream>>>(
      src, Xh, Wq, Wk, Wv, Wo, Wth, am, kp, amw, kpw);
  k_gemm_qkv<<<dim3(8,64,3), 256, 0, stream>>>(Xh, Wth, bq, bk, bv, Qh, Kh, Vt);
  k_flash<<<512, 256, 0, stream>>>(Qh, Kh, Vt, amw, kpw, stats, CT);
  k_oa<<<512*33, 256, 0, stream>>>(CT, Wth + 3*(size_t)D_*D_, bo, outp,
                                   Qh, Kh, amw, kpw, stats, attnp);
}